// Round 3
// baseline (604.563 us; speedup 1.0000x reference)
//
#include <hip/hip_runtime.h>
#include <math.h>

typedef _Float16 half_t;
typedef __attribute__((ext_vector_type(4))) _Float16 half4;
typedef __attribute__((ext_vector_type(8))) _Float16 half8;
typedef __attribute__((ext_vector_type(16))) float floatx16;

#define LO_SCALE 512.0f
#define INV_LO   0.001953125f  // 1/512

__device__ __forceinline__ float gelu_exact(float v) {
    return 0.5f * v * (1.0f + erff(v * 0.7071067811865476f));
}

__device__ __forceinline__ floatx16 zero16() {
    floatx16 z;
#pragma unroll
    for (int i = 0; i < 16; ++i) z[i] = 0.f;
    return z;
}

#define MFMA(a, b, c) __builtin_amdgcn_mfma_f32_32x32x16_f16((a), (b), (c), 0, 0, 0)

// ---------------- prep ----------------
// W [h][k][n] fp32 -> Wt [h][n][k] fp16 (transposed, hi only)
// Za tables [32][256]: row 2h = W[h]·A[h][0:256], 2h+1 = W[h]·A[h][256:512]
// Za lo plane scaled by 512 (keeps values in fp16 normal range).
__global__ __launch_bounds__(256) void prep(const float* __restrict__ W0,
                                            const float* __restrict__ A0,
                                            const float* __restrict__ W1,
                                            const float* __restrict__ A1,
                                            half_t* __restrict__ Wt0,
                                            half_t* __restrict__ Wt1,
                                            half_t* __restrict__ Za0h, half_t* __restrict__ Za0l,
                                            half_t* __restrict__ Za1h, half_t* __restrict__ Za1l) {
    __shared__ float tile[32][257];
    const int t = threadIdx.x;
    const int kb = blockIdx.x & 7;
    const int h  = (blockIdx.x >> 3) & 3;
    const int tz = blockIdx.x >> 5;
    const float* W = tz ? W1 : W0;
    const float* A = tz ? A1 : A0;
    half_t* Wt = tz ? Wt1 : Wt0;
    half_t* Zh = tz ? Za1h : Za0h;
    half_t* Zl = tz ? Za1l : Za0l;

    for (int i = 0; i < 32; ++i)
        tile[i][t] = W[(size_t)(h * 256 + kb * 32 + i) * 256 + t];
    __syncthreads();

    // thread t = n: write Wt[h][n][32kb .. +31]
    half_t hb[32];
#pragma unroll
    for (int i = 0; i < 32; ++i) hb[i] = (half_t)tile[i][t];
    size_t base = (size_t)(h * 256 + t) * 256 + kb * 32;
#pragma unroll
    for (int i = 0; i < 4; ++i)
        *(half8*)&Wt[base + 8 * i] = *(half8*)&hb[8 * i];

    if (kb == 0) {
        const float4* Wr = (const float4*)&W[(size_t)(h * 256 + t) * 256];
        const float4* Al = (const float4*)&A[h * 512];
        const float4* Ah = (const float4*)&A[h * 512 + 256];
        float wl = 0.f, wh = 0.f;
        for (int d = 0; d < 64; ++d) {
            float4 wv = Wr[d], a0 = Al[d], a1 = Ah[d];
            wl += wv.x * a0.x + wv.y * a0.y + wv.z * a0.z + wv.w * a0.w;
            wh += wv.x * a1.x + wv.y * a1.y + wv.z * a1.z + wv.w * a1.w;
        }
        half_t hi = (half_t)wl;
        Zh[(2 * h) * 256 + t] = hi;
        Zl[(2 * h) * 256 + t] = (half_t)((wl - (float)hi) * LO_SCALE);
        hi = (half_t)wh;
        Zh[(2 * h + 1) * 256 + t] = hi;
        Zl[(2 * h + 1) * 256 + t] = (half_t)((wh - (float)hi) * LO_SCALE);
        if (h == 0) {
            for (int c = 8; c < 32; ++c) {
                Zh[c * 256 + t] = (half_t)0.f;
                Zl[c * 256 + t] = (half_t)0.f;
            }
        }
    }
}

// ---------------- fused GAT layer ----------------
// x: [G][16][256] fp32; grid = G/GROUPS blocks of 256 thr; ROWS = 16*GROUPS.
// Wt: [4][256 n][256 k] fp16; Zah/Zal: [32][256] fp16; out: [G][256] fp32.
// Wave w owns cols [64w,64w+64). MFMA 32x32x16 f16, 2-pass x-split (lo scaled 512).
template <int GROUPS>
__global__ __launch_bounds__(256, 2) void gat_layer(
    const float* __restrict__ x,
    const half_t* __restrict__ Wt,
    const half_t* __restrict__ Zah, const half_t* __restrict__ Zal,
    float* __restrict__ out) {
    constexpr int ROWS = GROUPS * 16;
    constexpr int MT   = ROWS / 32;

    __shared__ half_t xs_hi[ROWS][264];
    __shared__ half_t xs_lo[ROWS][264];   // scaled by 512
    __shared__ float zlo_s[4][ROWS];
    __shared__ float zhi_s[4][ROWS];
    __shared__ float ge_s[4][ROWS];
    __shared__ float att_h[4][ROWS];      // head-major for float4 epilogue reads

    const int t  = threadIdx.x;
    const int w  = t >> 6;
    const int lm = t & 31;
    const int q  = (t >> 5) & 1;
    const size_t rowbase = (size_t)blockIdx.x * ROWS;

    // ---- stage x -> LDS fp16 hi + scaled lo ----
    {
        const float4* xg = (const float4*)(x + rowbase * 256);
#pragma unroll
        for (int i = 0; i < ROWS / 4; ++i) {
            int idx = t + 256 * i;
            int row = idx >> 6, c4 = idx & 63;
            float4 v = xg[idx];
            half_t h0 = (half_t)v.x, h1 = (half_t)v.y, h2 = (half_t)v.z, h3 = (half_t)v.w;
            half4 hv = {h0, h1, h2, h3};
            half4 lv = {(half_t)((v.x - (float)h0) * LO_SCALE),
                        (half_t)((v.y - (float)h1) * LO_SCALE),
                        (half_t)((v.z - (float)h2) * LO_SCALE),
                        (half_t)((v.w - (float)h3) * LO_SCALE)};
            *(half4*)&xs_hi[row][c4 * 4] = hv;
            *(half4*)&xs_lo[row][c4 * 4] = lv;
        }
    }
    __syncthreads();

    // ---- z-tile: z = x @ (W·A), all 4 heads in cols 0..7 ----
    {
        floatx16 zm[MT], zc[MT];
#pragma unroll
        for (int mt = 0; mt < MT; ++mt) { zm[mt] = zero16(); zc[mt] = zero16(); }
        const half_t* zbh = Zah + (size_t)lm * 256 + 8 * q;
        const half_t* zbl = Zal + (size_t)lm * 256 + 8 * q;
#pragma unroll 2
        for (int ks = 0; ks < 16; ++ks) {
            const int ke = 16 * ks;
            half8 bh = *(const half8*)(zbh + ke);
            half8 bl = *(const half8*)(zbl + ke);
#pragma unroll
            for (int mt = 0; mt < MT; ++mt) {
                half8 ah = *(const half8*)&xs_hi[32 * mt + lm][ke + 8 * q];
                half8 al = *(const half8*)&xs_lo[32 * mt + lm][ke + 8 * q];
                zm[mt] = MFMA(ah, bh, zm[mt]);
                zc[mt] = MFMA(al, bh, zc[mt]);   // 512*(xl·zah)
                zc[mt] = MFMA(ah, bl, zc[mt]);   // 512*(xh·zal)
            }
        }
        if (w == 0 && lm < 8) {
            int h = lm >> 1;
            float* dst = (lm & 1) ? &zhi_s[h][0] : &zlo_s[h][0];
#pragma unroll
            for (int mt = 0; mt < MT; ++mt)
#pragma unroll
                for (int r = 0; r < 16; ++r) {
                    int row = 32 * mt + 4 * q + (r & 3) + 8 * (r >> 2);
                    dst[row] = zm[mt][r] + zc[mt][r] * INV_LO;
                }
        }
    }
    __syncthreads();

    // ---- attention weights ----
    {
        int h = t >> 6, r = t & 63;
        if (r < ROWS) {
            float z = zlo_s[h][r] + zhi_s[h][r & ~15];
            ge_s[h][r] = gelu_exact(gelu_exact(z));
        }
    }
    __syncthreads();
    {
        int h = t >> 6, r = t & 63;
        if (r < ROWS) {
            int g0 = r & ~15;
            float mx = -1e30f;
#pragma unroll
            for (int i = 0; i < 16; ++i) mx = fmaxf(mx, ge_s[h][g0 + i]);
            float s = 0.f;
#pragma unroll
            for (int i = 0; i < 16; ++i) s += expf(ge_s[h][g0 + i] - mx);
            att_h[h][r] = expf(ge_s[h][r] - mx) / s;
        }
    }
    __syncthreads();

    // ---- main GEMM: one head per iter, distance-2 B prefetch, 2-pass split ----
    float outacc[GROUPS][2];
#pragma unroll
    for (int g = 0; g < GROUPS; ++g) { outacc[g][0] = 0.f; outacc[g][1] = 0.f; }

#pragma unroll 1
    for (int h = 0; h < 4; ++h) {
        const half_t* bp0 = Wt + ((size_t)(h * 256 + 64 * w + lm) * 256) + 8 * q;
        const half_t* bp1 = bp0 + 32 * 256;

        half8 b0[2], b1[2];
        b0[0] = *(const half8*)(bp0);
        b0[1] = *(const half8*)(bp0 + 16);
        b1[0] = *(const half8*)(bp1);
        b1[1] = *(const half8*)(bp1 + 16);

        floatx16 am0[MT], ac0[MT], am1[MT], ac1[MT];
#pragma unroll
        for (int mt = 0; mt < MT; ++mt) {
            am0[mt] = zero16(); ac0[mt] = zero16();
            am1[mt] = zero16(); ac1[mt] = zero16();
        }

#pragma unroll
        for (int ks = 0; ks < 16; ++ks) {
            const int ke = 16 * ks;
            half8 ah[MT], al[MT];
#pragma unroll
            for (int mt = 0; mt < MT; ++mt) {
                ah[mt] = *(const half8*)&xs_hi[32 * mt + lm][ke + 8 * q];
                al[mt] = *(const half8*)&xs_lo[32 * mt + lm][ke + 8 * q];
            }
#pragma unroll
            for (int mt = 0; mt < MT; ++mt) {
                am0[mt] = MFMA(ah[mt], b0[ks & 1], am0[mt]);
                am1[mt] = MFMA(ah[mt], b1[ks & 1], am1[mt]);
                ac0[mt] = MFMA(al[mt], b0[ks & 1], ac0[mt]);
                ac1[mt] = MFMA(al[mt], b1[ks & 1], ac1[mt]);
            }
            // prefetch ks+2 into the slot just consumed
            if (ks < 14) {
                b0[ks & 1] = *(const half8*)(bp0 + ke + 32);
                b1[ks & 1] = *(const half8*)(bp1 + ke + 32);
            }
        }

        // ---- per-head epilogue: att-weighted row sum, gelu, head-mean ----
        float tp[2][GROUPS];
#pragma unroll
        for (int g = 0; g < GROUPS; ++g) { tp[0][g] = 0.f; tp[1][g] = 0.f; }
#pragma unroll
        for (int mt = 0; mt < MT; ++mt)
#pragma unroll
            for (int k = 0; k < 4; ++k) {
                float4 a4 = *(const float4*)&att_h[h][32 * mt + 4 * q + 8 * k];
#pragma unroll
                for (int j = 0; j < 4; ++j) {
                    int r = 4 * k + j;
                    int row = 32 * mt + 4 * q + 8 * k + j;
                    int g = row >> 4;
                    float av = (&a4.x)[j];
                    tp[0][g] = fmaf(am0[mt][r] + ac0[mt][r] * INV_LO, av, tp[0][g]);
                    tp[1][g] = fmaf(am1[mt][r] + ac1[mt][r] * INV_LO, av, tp[1][g]);
                }
            }
#pragma unroll
        for (int nt = 0; nt < 2; ++nt)
#pragma unroll
            for (int g = 0; g < GROUPS; ++g) {
                float s = tp[nt][g] + __shfl_xor(tp[nt][g], 32, 64);
                outacc[g][nt] += 0.25f * gelu_exact(s);
            }
    }

    // ---- store ----
    if (q == 0) {
#pragma unroll
        for (int g = 0; g < GROUPS; ++g) {
            size_t ro = ((size_t)blockIdx.x * GROUPS + g) * 256 + 64 * w;
            out[ro + lm]      = outacc[g][0];
            out[ro + 32 + lm] = outacc[g][1];
        }
    }
}

extern "C" void kernel_launch(void* const* d_in, const int* in_sizes, int n_in,
                              void* d_out, int out_size, void* d_ws, size_t ws_size,
                              hipStream_t stream) {
    const float* x  = (const float*)d_in[0];
    const float* W0 = (const float*)d_in[1];
    const float* A0 = (const float*)d_in[2];
    const float* W1 = (const float*)d_in[3];
    const float* A1 = (const float*)d_in[4];

    char* ws = (char*)d_ws;
    float*  y1   = (float*)ws;                  // 8 MiB: [8192][256]
    half_t* Wt0  = (half_t*)(ws + 8388608);     // 512 KiB
    half_t* Wt1  = (half_t*)(ws + 8912896);     // 512 KiB
    half_t* Za0h = (half_t*)(ws + 9437184);     // 16 KiB each
    half_t* Za0l = (half_t*)(ws + 9453568);
    half_t* Za1h = (half_t*)(ws + 9469952);
    half_t* Za1l = (half_t*)(ws + 9486336);

    prep<<<64, 256, 0, stream>>>(W0, A0, W1, A1, Wt0, Wt1, Za0h, Za0l, Za1h, Za1l);
    gat_layer<4><<<2048, 256, 0, stream>>>(x, Wt0, Za0h, Za0l, y1);
    gat_layer<2><<<256, 256, 0, stream>>>(y1, Wt1, Za1h, Za1l, (float*)d_out);
}

// Round 4
// 586.640 us; speedup vs baseline: 1.0306x; 1.0306x over previous
//
#include <hip/hip_runtime.h>
#include <hip/hip_fp8.h>
#include <math.h>

typedef _Float16 half_t;
typedef __attribute__((ext_vector_type(4))) _Float16 half4;
typedef __attribute__((ext_vector_type(8))) _Float16 half8;
typedef __attribute__((ext_vector_type(16))) float floatx16;

#define LO_SCALE 512.0f
#define INV_LO   0.001953125f  // 1/512

__device__ __forceinline__ float gelu_exact(float v) {
    return 0.5f * v * (1.0f + erff(v * 0.7071067811865476f));
}

__device__ __forceinline__ floatx16 zero16() {
    floatx16 z;
#pragma unroll
    for (int i = 0; i < 16; ++i) z[i] = 0.f;
    return z;
}

__device__ __forceinline__ unsigned char to_fp8(float v) {
    __hip_fp8_e4m3 f(v);
    return f.__x;
}

#define MFMA16(a, b, c) __builtin_amdgcn_mfma_f32_32x32x16_f16((a), (b), (c), 0, 0, 0)
#define MFMA8(a, b, c)  __builtin_amdgcn_mfma_f32_32x32x16_fp8_fp8((a), (b), (c), 0, 0, 0)

// ---------------- prep ----------------
// W [h][k][n] fp32 -> Wsw16/Wsw8: MFMA-B-fragment-swizzled [h][ks][j][lane][8]
//   element (n,k): j=n>>5, lane=32*((k>>3)&1)+(n&31), ks=k>>4, jj=k&7
// Za tables [32 n][256 k]: row 2h = W[h]·A[h][0:256], row 2h+1 = W[h]·A[h][256:512]
//   Zah fp16 hi, Zal fp16 (lo*512), Za8 fp8(full value)
__global__ __launch_bounds__(256) void prep(const float* __restrict__ W0,
                                            const float* __restrict__ A0,
                                            const float* __restrict__ W1,
                                            const float* __restrict__ A1,
                                            half_t* __restrict__ Wsw16_0, half_t* __restrict__ Wsw16_1,
                                            unsigned char* __restrict__ Wsw8_0, unsigned char* __restrict__ Wsw8_1,
                                            half_t* __restrict__ Zah0, half_t* __restrict__ Zal0,
                                            unsigned char* __restrict__ Za8_0,
                                            half_t* __restrict__ Zah1, half_t* __restrict__ Zal1,
                                            unsigned char* __restrict__ Za8_1) {
    __shared__ float tile[32][257];
    const int t  = threadIdx.x;
    const int kb = blockIdx.x & 7;
    const int h  = (blockIdx.x >> 3) & 3;
    const int tz = blockIdx.x >> 5;
    const float* W = tz ? W1 : W0;
    const float* A = tz ? A1 : A0;
    half_t* W16 = tz ? Wsw16_1 : Wsw16_0;
    unsigned char* W8 = tz ? Wsw8_1 : Wsw8_0;
    half_t* Zh = tz ? Zah1 : Zah0;
    half_t* Zl = tz ? Zal1 : Zal0;
    unsigned char* Z8 = tz ? Za8_1 : Za8_0;

    for (int i = 0; i < 32; ++i)
        tile[i][t] = W[(size_t)(h * 256 + kb * 32 + i) * 256 + t];
    __syncthreads();

    const int j = t >> 5, lmn = t & 31;
#pragma unroll
    for (int i0 = 0; i0 < 32; i0 += 8) {
        const int ks = 2 * kb + (i0 >> 4);
        const int q  = (i0 >> 3) & 1;
        half_t hb[8];
        unsigned long long pk = 0ull;
#pragma unroll
        for (int ii = 0; ii < 8; ++ii) {
            float v = tile[i0 + ii][t];
            hb[ii] = (half_t)v;
            pk |= ((unsigned long long)to_fp8(v)) << (8 * ii);
        }
        size_t off = ((size_t)(h * 16 + ks) * 8 + j) * 512 + (size_t)(32 * q + lmn) * 8;
        *(half8*)&W16[off] = *(half8*)hb;
        *(unsigned long long*)&W8[off] = pk;
    }

    if (kb == 0) {
        const float4* Wr = (const float4*)&W[(size_t)(h * 256 + t) * 256];
        const float4* Al = (const float4*)&A[h * 512];
        const float4* Ah = (const float4*)&A[h * 512 + 256];
        float wl = 0.f, wh = 0.f;
        for (int d = 0; d < 64; ++d) {
            float4 wv = Wr[d], a0 = Al[d], a1 = Ah[d];
            wl += wv.x * a0.x + wv.y * a0.y + wv.z * a0.z + wv.w * a0.w;
            wh += wv.x * a1.x + wv.y * a1.y + wv.z * a1.z + wv.w * a1.w;
        }
        half_t hi = (half_t)wl;
        Zh[(2 * h) * 256 + t] = hi;
        Zl[(2 * h) * 256 + t] = (half_t)((wl - (float)hi) * LO_SCALE);
        Z8[(2 * h) * 256 + t] = to_fp8(wl);
        hi = (half_t)wh;
        Zh[(2 * h + 1) * 256 + t] = hi;
        Zl[(2 * h + 1) * 256 + t] = (half_t)((wh - (float)hi) * LO_SCALE);
        Z8[(2 * h + 1) * 256 + t] = to_fp8(wh);
        if (h == 0) {
            for (int c = 8; c < 32; ++c) {
                Zh[c * 256 + t] = (half_t)0.f;
                Zl[c * 256 + t] = (half_t)0.f;
                Z8[c * 256 + t] = 0;
            }
        }
    }
}

// ---------------- fused GAT layer ----------------
// x: [G][16][256] fp32; ROWS=16*GROUPS per block; grid = totalrows/ROWS, 256 thr.
// xsh/xsl: x staged as MFMA A-fragments (hi fp16, lo*512 fp8), conflict-free reads.
// Main GEMM: wave w -> colhalf ch=w&1 (128 cols), heads {2*(w>>1), 2*(w>>1)+1};
// per head: pass1 f16 (x_hi*W16), pass2 fp8 (512*x_lo * W8), combined via linear
// att-weighted sum tp (+= pass2 * 1/512), then gelu and head accumulation.
template <int GROUPS>
__global__ __launch_bounds__(256, 2) void gat_layer(
    const float* __restrict__ x,
    const half_t* __restrict__ Wsw16, const unsigned char* __restrict__ Wsw8,
    const half_t* __restrict__ Zah, const half_t* __restrict__ Zal,
    const unsigned char* __restrict__ Za8,
    float* __restrict__ out) {
    constexpr int ROWS = GROUPS * 16;
    constexpr int MT   = (GROUPS + 1) / 2;   // 4->2, 2->1

    __shared__ half_t        xsh[MT * 16 * 512];   // A-frags fp16 hi
    __shared__ unsigned char xsl[MT * 16 * 512];   // A-frags fp8 (lo*512)
    __shared__ float zlo_s[4][ROWS];
    __shared__ float zhi_s[4][ROWS];
    __shared__ float ge_s[4][ROWS];
    __shared__ float att_s[4][ROWS];
    __shared__ float slab[2][GROUPS][256];

    const int t  = threadIdx.x;
    const int w  = t >> 6;
    const int l  = t & 63;
    const int lm = t & 31;
    const int q  = (t >> 5) & 1;   // == (l>>5)&1

    // ---- stage x -> LDS fragment layout ----
    {
        const float4* xg = (const float4*)(x + (size_t)blockIdx.x * ROWS * 256);
#pragma unroll
        for (int i = 0; i < ROWS / 4; ++i) {
            int idx = t + 256 * i;
            int row = idx >> 6, c = idx & 63;
            float4 v = xg[idx];
            int m = row >> 5, r31 = row & 31;
            int ks = c >> 2, qq = (c >> 1) & 1, jo = (c & 1) * 4;
            half_t h0 = (half_t)v.x, h1 = (half_t)v.y, h2 = (half_t)v.z, h3 = (half_t)v.w;
            half4 hv = {h0, h1, h2, h3};
            unsigned int pk = (unsigned int)to_fp8((v.x - (float)h0) * LO_SCALE)
                            | ((unsigned int)to_fp8((v.y - (float)h1) * LO_SCALE) << 8)
                            | ((unsigned int)to_fp8((v.z - (float)h2) * LO_SCALE) << 16)
                            | ((unsigned int)to_fp8((v.w - (float)h3) * LO_SCALE) << 24);
            int base = ((m * 16 + ks) * 64 + 32 * qq + r31) * 8 + jo;
            *(half4*)&xsh[base] = hv;
            *(unsigned int*)&xsl[base] = pk;
        }
    }
    __syncthreads();

    // ---- z-tile: z = x @ (W·A), all 4 heads in cols 0..7 ----
    {
        floatx16 zm[MT], zc[MT], z8[MT];
#pragma unroll
        for (int mt = 0; mt < MT; ++mt) { zm[mt] = zero16(); zc[mt] = zero16(); z8[mt] = zero16(); }
#pragma unroll 4
        for (int ks = 0; ks < 16; ++ks) {
            const int ko = lm * 256 + 16 * ks + 8 * q;
            half8 bh = *(const half8*)&Zah[ko];
            half8 bl = *(const half8*)&Zal[ko];
            long  b8 = *(const long*)&Za8[ko];
#pragma unroll
            for (int mt = 0; mt < MT; ++mt) {
                half8 a  = *(const half8*)&xsh[((mt * 16 + ks) * 64 + l) * 8];
                long  a8 = *(const long*)&xsl[((mt * 16 + ks) * 64 + l) * 8];
                zm[mt] = MFMA16(a, bh, zm[mt]);
                zc[mt] = MFMA16(a, bl, zc[mt]);
                z8[mt] = MFMA8(a8, b8, z8[mt]);
            }
        }
        if (w == 0 && lm < 8) {
            int h = lm >> 1;
            float* dst = (lm & 1) ? &zhi_s[h][0] : &zlo_s[h][0];
#pragma unroll
            for (int mt = 0; mt < MT; ++mt)
#pragma unroll
                for (int r = 0; r < 16; ++r) {
                    int row = 32 * mt + 4 * q + (r & 3) + 8 * (r >> 2);
                    dst[row] = zm[mt][r] + (zc[mt][r] + z8[mt][r]) * INV_LO;
                }
        }
    }
    __syncthreads();

    // ---- attention weights ----
    {
        int h = t >> 6, r = t & 63;
        if (r < ROWS) {
            float z = zlo_s[h][r] + zhi_s[h][r & ~15];
            ge_s[h][r] = gelu_exact(gelu_exact(z));
        }
    }
    __syncthreads();
    {
        int h = t >> 6, r = t & 63;
        if (r < ROWS) {
            int g0 = r & ~15;
            float mx = -1e30f;
#pragma unroll
            for (int i = 0; i < 16; ++i) mx = fmaxf(mx, ge_s[h][g0 + i]);
            float s = 0.f;
#pragma unroll
            for (int i = 0; i < 16; ++i) s += expf(ge_s[h][g0 + i] - mx);
            att_s[h][r] = expf(ge_s[h][r] - mx) / s;
        }
    }
    __syncthreads();

    // ---- main GEMM ----
    const int ch = w & 1;
    const int hbase = 2 * (w >> 1);
    float outp[4][GROUPS];
#pragma unroll
    for (int nt = 0; nt < 4; ++nt)
#pragma unroll
        for (int g = 0; g < GROUPS; ++g) outp[nt][g] = 0.f;

#pragma unroll 1
    for (int hp = 0; hp < 2; ++hp) {
        const int h = hbase + hp;
        float tp[4][GROUPS];
#pragma unroll
        for (int nt = 0; nt < 4; ++nt)
#pragma unroll
            for (int g = 0; g < GROUPS; ++g) tp[nt][g] = 0.f;

        // ---- pass 1: fp16 hi ----
        {
            floatx16 acc[MT][4];
#pragma unroll
            for (int mt = 0; mt < MT; ++mt)
#pragma unroll
                for (int nt = 0; nt < 4; ++nt) acc[mt][nt] = zero16();
            const half_t* Bp = Wsw16 + ((size_t)h * 128 + 4 * ch) * 512 + (size_t)l * 8;
#pragma unroll 4
            for (int ks = 0; ks < 16; ++ks) {
                half8 a[MT];
#pragma unroll
                for (int mt = 0; mt < MT; ++mt)
                    a[mt] = *(const half8*)&xsh[((mt * 16 + ks) * 64 + l) * 8];
#pragma unroll
                for (int nt = 0; nt < 4; ++nt) {
                    half8 b = *(const half8*)(Bp + (size_t)(ks * 8 + nt) * 512);
#pragma unroll
                    for (int mt = 0; mt < MT; ++mt)
                        acc[mt][nt] = MFMA16(a[mt], b, acc[mt][nt]);
                }
            }
#pragma unroll
            for (int mt = 0; mt < MT; ++mt)
#pragma unroll
                for (int k = 0; k < 4; ++k) {
                    float4 a4 = *(const float4*)&att_s[h][32 * mt + 4 * q + 8 * k];
#pragma unroll
                    for (int jj = 0; jj < 4; ++jj) {
                        int r = 4 * k + jj;
                        int g = 2 * mt + (r >> 3);
                        float av = (&a4.x)[jj];
#pragma unroll
                        for (int nt = 0; nt < 4; ++nt)
                            tp[nt][g] = fmaf(acc[mt][nt][r], av, tp[nt][g]);
                    }
                }
        }

        // ---- pass 2: fp8 lo correction (x_lo*512 · W) ----
        {
            floatx16 acc[MT][4];
#pragma unroll
            for (int mt = 0; mt < MT; ++mt)
#pragma unroll
                for (int nt = 0; nt < 4; ++nt) acc[mt][nt] = zero16();
            const unsigned char* Bp = Wsw8 + ((size_t)h * 128 + 4 * ch) * 512 + (size_t)l * 8;
#pragma unroll 4
            for (int ks = 0; ks < 16; ++ks) {
                long a[MT];
#pragma unroll
                for (int mt = 0; mt < MT; ++mt)
                    a[mt] = *(const long*)&xsl[((mt * 16 + ks) * 64 + l) * 8];
#pragma unroll
                for (int nt = 0; nt < 4; ++nt) {
                    long b = *(const long*)(Bp + (size_t)(ks * 8 + nt) * 512);
#pragma unroll
                    for (int mt = 0; mt < MT; ++mt)
                        acc[mt][nt] = MFMA8(a[mt], b, acc[mt][nt]);
                }
            }
#pragma unroll
            for (int mt = 0; mt < MT; ++mt)
#pragma unroll
                for (int k = 0; k < 4; ++k) {
                    float4 a4 = *(const float4*)&att_s[h][32 * mt + 4 * q + 8 * k];
#pragma unroll
                    for (int jj = 0; jj < 4; ++jj) {
                        int r = 4 * k + jj;
                        int g = 2 * mt + (r >> 3);
                        float av = (&a4.x)[jj] * INV_LO;
#pragma unroll
                        for (int nt = 0; nt < 4; ++nt)
                            tp[nt][g] = fmaf(acc[mt][nt][r], av, tp[nt][g]);
                    }
                }
        }

        // ---- fold q-halves, gelu, accumulate over this wave's heads ----
#pragma unroll
        for (int nt = 0; nt < 4; ++nt)
#pragma unroll
            for (int g = 0; g < GROUPS; ++g) {
                float s = tp[nt][g] + __shfl_xor(tp[nt][g], 32, 64);
                outp[nt][g] += gelu_exact(s);
            }
    }

    // ---- slab write (one owner wave per slot) ----
    if (q == 0) {
#pragma unroll
        for (int nt = 0; nt < 4; ++nt)
#pragma unroll
            for (int g = 0; g < GROUPS; ++g)
                slab[w >> 1][g][128 * ch + 32 * nt + lm] = outp[nt][g];
    }
    __syncthreads();

#pragma unroll
    for (int g = 0; g < GROUPS; ++g)
        out[((size_t)blockIdx.x * GROUPS + g) * 256 + t] =
            0.25f * (slab[0][g][t] + slab[1][g][t]);
}

extern "C" void kernel_launch(void* const* d_in, const int* in_sizes, int n_in,
                              void* d_out, int out_size, void* d_ws, size_t ws_size,
                              hipStream_t stream) {
    const float* x  = (const float*)d_in[0];
    const float* W0 = (const float*)d_in[1];
    const float* A0 = (const float*)d_in[2];
    const float* W1 = (const float*)d_in[3];
    const float* A1 = (const float*)d_in[4];

    char* ws = (char*)d_ws;
    float*         y1      = (float*)ws;                         // 8 MiB
    half_t*        Wsw16_0 = (half_t*)(ws + 8388608);            // 512 KiB
    half_t*        Wsw16_1 = (half_t*)(ws + 8912896);            // 512 KiB
    unsigned char* Wsw8_0  = (unsigned char*)(ws + 9437184);     // 256 KiB
    unsigned char* Wsw8_1  = (unsigned char*)(ws + 9699328);     // 256 KiB
    half_t*        Zah0    = (half_t*)(ws + 9961472);            // 16 KiB
    half_t*        Zal0    = (half_t*)(ws + 9977856);
    half_t*        Zah1    = (half_t*)(ws + 9994240);
    half_t*        Zal1    = (half_t*)(ws + 10010624);
    unsigned char* Za8_0   = (unsigned char*)(ws + 10027008);    // 8 KiB
    unsigned char* Za8_1   = (unsigned char*)(ws + 10035200);

    prep<<<64, 256, 0, stream>>>(W0, A0, W1, A1, Wsw16_0, Wsw16_1, Wsw8_0, Wsw8_1,
                                 Zah0, Zal0, Za8_0, Zah1, Zal1, Za8_1);
    gat_layer<4><<<2048, 256, 0, stream>>>(x, Wsw16_0, Wsw8_0, Zah0, Zal0, Za8_0, y1);
    gat_layer<2><<<256, 256, 0, stream>>>(y1, Wsw16_1, Wsw8_1, Zah1, Zal1, Za8_1,
                                          (float*)d_out);
}

// Round 5
// 346.556 us; speedup vs baseline: 1.7445x; 1.6928x over previous
//
#include <hip/hip_runtime.h>
#include <math.h>

typedef _Float16 half_t;
typedef __attribute__((ext_vector_type(8))) _Float16 half8;
typedef __attribute__((ext_vector_type(16))) float floatx16;

__device__ __forceinline__ float gelu_exact(float v) {
    return 0.5f * v * (1.0f + erff(v * 0.7071067811865476f));
}

__device__ __forceinline__ floatx16 zero16() {
    floatx16 z;
#pragma unroll
    for (int i = 0; i < 16; ++i) z[i] = 0.f;
    return z;
}

#define MFMA16(a, b, c) __builtin_amdgcn_mfma_f32_32x32x16_f16((a), (b), (c), 0, 0, 0)

// ---------------- prep ----------------
// W [h][k][n] fp32 -> Wsw: B-fragment-swizzled f16 [h][ks][j][l][jj]
//   element (k,n): ks=k>>4, j=n>>5, l=32*((k>>3)&1)+(n&31), jj=k&7
//   (validated: rounds 3/4 passed with this mapping)
// Za tables [32 n][256 k] f16: row 2h = W[h]·A[h][0:256], 2h+1 = W[h]·A[h][256:512]
//   Zah = hi, Zal = residual (unscaled; f16 holds ~1e-4 fine)
__global__ __launch_bounds__(256) void prep(const float* __restrict__ W0,
                                            const float* __restrict__ A0,
                                            const float* __restrict__ W1,
                                            const float* __restrict__ A1,
                                            half_t* __restrict__ Wsw0, half_t* __restrict__ Wsw1,
                                            half_t* __restrict__ Zah0, half_t* __restrict__ Zal0,
                                            half_t* __restrict__ Zah1, half_t* __restrict__ Zal1) {
    __shared__ float tile[32][257];
    const int t  = threadIdx.x;
    const int kb = blockIdx.x & 7;
    const int h  = (blockIdx.x >> 3) & 3;
    const int tz = blockIdx.x >> 5;
    const float* W = tz ? W1 : W0;
    const float* A = tz ? A1 : A0;
    half_t* Wsw = tz ? Wsw1 : Wsw0;
    half_t* Zh  = tz ? Zah1 : Zah0;
    half_t* Zl  = tz ? Zal1 : Zal0;

    for (int i = 0; i < 32; ++i)
        tile[i][t] = W[(size_t)(h * 256 + kb * 32 + i) * 256 + t];
    __syncthreads();

    const int j = t >> 5, lmn = t & 31;
#pragma unroll
    for (int i0 = 0; i0 < 32; i0 += 8) {
        const int ks = 2 * kb + (i0 >> 4);
        const int q  = (i0 >> 3) & 1;
        half_t hb[8];
#pragma unroll
        for (int ii = 0; ii < 8; ++ii) hb[ii] = (half_t)tile[i0 + ii][t];
        size_t off = ((size_t)(h * 16 + ks) * 8 + j) * 512 + (size_t)(32 * q + lmn) * 8;
        *(half8*)&Wsw[off] = *(half8*)hb;
    }

    if (kb == 0) {
        const float4* Wr = (const float4*)&W[(size_t)(h * 256 + t) * 256];
        const float4* Al = (const float4*)&A[h * 512];
        const float4* Ah = (const float4*)&A[h * 512 + 256];
        float wl = 0.f, wh = 0.f;
        for (int d = 0; d < 64; ++d) {
            float4 wv = Wr[d], a0 = Al[d], a1 = Ah[d];
            wl += wv.x * a0.x + wv.y * a0.y + wv.z * a0.z + wv.w * a0.w;
            wh += wv.x * a1.x + wv.y * a1.y + wv.z * a1.z + wv.w * a1.w;
        }
        half_t hi = (half_t)wl;
        Zh[(2 * h) * 256 + t] = hi;
        Zl[(2 * h) * 256 + t] = (half_t)(wl - (float)hi);
        hi = (half_t)wh;
        Zh[(2 * h + 1) * 256 + t] = hi;
        Zl[(2 * h + 1) * 256 + t] = (half_t)(wh - (float)hi);
        if (h == 0) {
            for (int c = 8; c < 32; ++c) {
                Zh[c * 256 + t] = (half_t)0.f;
                Zl[c * 256 + t] = (half_t)0.f;
            }
        }
    }
}

// ---------------- fused GAT layer ----------------
// ROWS = 16*GROUPS rows per block; wave w owns cols [64w, 64w+64) of each head.
// Sequential numeric passes per head (hi, then lo residual) into ONE acc set
// -> 64 live acc regs, no spill at __launch_bounds__(256,2).
template <int GROUPS>
__global__ __launch_bounds__(256, 2) void gat_layer(
    const float* __restrict__ x,
    const half_t* __restrict__ Wsw,
    const half_t* __restrict__ Zah, const half_t* __restrict__ Zal,
    float* __restrict__ out) {
    constexpr int ROWS = GROUPS * 16;
    constexpr int MT   = ROWS / 32;

    __shared__ half_t xsh[MT * 16 * 512];   // A-frags f16 hi   [mt][ks][64 lanes][8]
    __shared__ half_t xsl[MT * 16 * 512];   // A-frags f16 lo residual
    __shared__ float zlo_s[4][ROWS];
    __shared__ float zhi_s[4][ROWS];
    __shared__ float ge_s[4][ROWS];
    __shared__ float att_s[4][ROWS];

    const int t  = threadIdx.x;
    const int w  = t >> 6;
    const int l  = t & 63;
    const int lm = t & 31;
    const int q  = (t >> 5) & 1;

    // ---- stage x -> LDS A-fragment layout (b128 writes, stride-16 canonical) ----
    {
        const float4* xg = (const float4*)(x + (size_t)blockIdx.x * ROWS * 256);
#pragma unroll
        for (int i = 0; i < ROWS / 8; ++i) {
            int e = t + 256 * i;
            int row = e >> 5, cc = e & 31;          // k chunk of 8: k0 = 8*cc
            float4 v0 = xg[row * 64 + 2 * cc];
            float4 v1 = xg[row * 64 + 2 * cc + 1];
            half_t hb[8], lb[8];
            const float* vf = &v0.x;
#pragma unroll
            for (int ii = 0; ii < 8; ++ii) {
                float v = (ii < 4) ? vf[ii] : (&v1.x)[ii - 4];
                half_t hv = (half_t)v;
                hb[ii] = hv;
                lb[ii] = (half_t)(v - (float)hv);
            }
            int m = row >> 5, r31 = row & 31, ks = cc >> 1, kq = cc & 1;
            int base = ((m * 16 + ks) * 64 + 32 * kq + r31) * 8;
            *(half8*)&xsh[base] = *(half8*)hb;
            *(half8*)&xsl[base] = *(half8*)lb;
        }
    }
    __syncthreads();

    // ---- z-tile (wave 0 only): z = x @ (W·A), all 4 heads in cols 0..7 ----
    if (w == 0) {
        floatx16 zm[MT], zc[MT];
#pragma unroll
        for (int mt = 0; mt < MT; ++mt) { zm[mt] = zero16(); zc[mt] = zero16(); }
#pragma unroll 4
        for (int ks = 0; ks < 16; ++ks) {
            const int ko = lm * 256 + 16 * ks + 8 * q;
            half8 bh = *(const half8*)&Zah[ko];
            half8 bl = *(const half8*)&Zal[ko];
#pragma unroll
            for (int mt = 0; mt < MT; ++mt) {
                half8 a  = *(const half8*)&xsh[((mt * 16 + ks) * 64 + l) * 8];
                half8 al = *(const half8*)&xsl[((mt * 16 + ks) * 64 + l) * 8];
                zm[mt] = MFMA16(a, bh, zm[mt]);
                zc[mt] = MFMA16(al, bh, zc[mt]);
                zc[mt] = MFMA16(a, bl, zc[mt]);
            }
        }
        if (lm < 8) {
            int h = lm >> 1;
            float* dst = (lm & 1) ? &zhi_s[h][0] : &zlo_s[h][0];
#pragma unroll
            for (int mt = 0; mt < MT; ++mt)
#pragma unroll
                for (int r = 0; r < 16; ++r) {
                    int row = 32 * mt + 4 * q + (r & 3) + 8 * (r >> 2);
                    dst[row] = zm[mt][r] + zc[mt][r];
                }
        }
    }
    __syncthreads();

    // ---- attention weights ----
    {
        int h = t >> 6, r = t & 63;
        if (r < ROWS) {
            float z = zlo_s[h][r] + zhi_s[h][r & ~15];
            ge_s[h][r] = gelu_exact(gelu_exact(z));
        }
    }
    __syncthreads();
    {
        int h = t >> 6, r = t & 63;
        if (r < ROWS) {
            int g0 = r & ~15;
            float mx = -1e30f;
#pragma unroll
            for (int i = 0; i < 16; ++i) mx = fmaxf(mx, ge_s[h][g0 + i]);
            float s = 0.f;
#pragma unroll
            for (int i = 0; i < 16; ++i) s += expf(ge_s[h][g0 + i] - mx);
            att_s[h][r] = expf(ge_s[h][r] - mx) / s;
        }
    }
    __syncthreads();

    // ---- main GEMM: per head, sequential hi/lo passes into one acc set ----
    float outp[2][GROUPS];
#pragma unroll
    for (int nt = 0; nt < 2; ++nt)
#pragma unroll
        for (int g = 0; g < GROUPS; ++g) outp[nt][g] = 0.f;

#pragma unroll 1
    for (int h = 0; h < 4; ++h) {
        float tp[2][GROUPS];
#pragma unroll
        for (int nt = 0; nt < 2; ++nt)
#pragma unroll
            for (int g = 0; g < GROUPS; ++g) tp[nt][g] = 0.f;

        const half_t* Bp = Wsw + ((size_t)(h * 16) * 8 + 2 * w) * 512 + (size_t)l * 8;

#pragma unroll 1
        for (int pass = 0; pass < 2; ++pass) {
            const half_t* Xp = pass ? xsl : xsh;
            floatx16 acc[MT][2];
#pragma unroll
            for (int mt = 0; mt < MT; ++mt) { acc[mt][0] = zero16(); acc[mt][1] = zero16(); }

#pragma unroll
            for (int ks = 0; ks < 16; ++ks) {
                half8 b0 = *(const half8*)(Bp + (size_t)ks * 4096);
                half8 b1 = *(const half8*)(Bp + (size_t)ks * 4096 + 512);
#pragma unroll
                for (int mt = 0; mt < MT; ++mt) {
                    half8 a = *(const half8*)&Xp[((mt * 16 + ks) * 64 + l) * 8];
                    acc[mt][0] = MFMA16(a, b0, acc[mt][0]);
                    acc[mt][1] = MFMA16(a, b1, acc[mt][1]);
                }
            }

            // fold this pass into tp (linear att-weighted row sum)
#pragma unroll
            for (int mt = 0; mt < MT; ++mt)
#pragma unroll
                for (int k = 0; k < 4; ++k) {
                    float4 a4 = *(const float4*)&att_s[h][32 * mt + 4 * q + 8 * k];
#pragma unroll
                    for (int jj = 0; jj < 4; ++jj) {
                        int r = 4 * k + jj;
                        int row = 32 * mt + 4 * q + 8 * k + jj;
                        int g = row >> 4;
                        float av = (&a4.x)[jj];
                        tp[0][g] = fmaf(acc[mt][0][r], av, tp[0][g]);
                        tp[1][g] = fmaf(acc[mt][1][r], av, tp[1][g]);
                    }
                }
        }

        // gelu + head accumulation (fold q-halves)
#pragma unroll
        for (int nt = 0; nt < 2; ++nt)
#pragma unroll
            for (int g = 0; g < GROUPS; ++g) {
                float s = tp[nt][g] + __shfl_xor(tp[nt][g], 32, 64);
                outp[nt][g] += gelu_exact(s);
            }
    }

    // ---- store: wave w owns cols 64w..64w+63 of every head -> direct global ----
    if (q == 0) {
#pragma unroll
        for (int g = 0; g < GROUPS; ++g) {
            size_t ro = ((size_t)blockIdx.x * GROUPS + g) * 256 + 64 * w;
            out[ro + lm]      = 0.25f * outp[0][g];
            out[ro + 32 + lm] = 0.25f * outp[1][g];
        }
    }
}

extern "C" void kernel_launch(void* const* d_in, const int* in_sizes, int n_in,
                              void* d_out, int out_size, void* d_ws, size_t ws_size,
                              hipStream_t stream) {
    const float* x  = (const float*)d_in[0];
    const float* W0 = (const float*)d_in[1];
    const float* A0 = (const float*)d_in[2];
    const float* W1 = (const float*)d_in[3];
    const float* A1 = (const float*)d_in[4];

    char* ws = (char*)d_ws;
    float*  y1   = (float*)ws;                  // 8 MiB: [8192][256]
    half_t* Wsw0 = (half_t*)(ws + 8388608);     // 512 KiB
    half_t* Wsw1 = (half_t*)(ws + 8912896);     // 512 KiB
    half_t* Zah0 = (half_t*)(ws + 9437184);     // 16 KiB each
    half_t* Zal0 = (half_t*)(ws + 9453568);
    half_t* Zah1 = (half_t*)(ws + 9469952);
    half_t* Zal1 = (half_t*)(ws + 9486336);

    prep<<<64, 256, 0, stream>>>(W0, A0, W1, A1, Wsw0, Wsw1, Zah0, Zal0, Zah1, Zal1);
    gat_layer<4><<<2048, 256, 0, stream>>>(x, Wsw0, Zah0, Zal0, y1);
    gat_layer<2><<<256, 256, 0, stream>>>(y1, Wsw1, Zah1, Zal1, (float*)d_out);
}